// Round 9
// baseline (332.293 us; speedup 1.0000x reference)
//
#include <hip/hip_runtime.h>
#include <hip/hip_bf16.h>

// HybridEstimator: 3-layer tanh MLP (f16 MFMA) + quantum epilogue + matvec.
// Round 9: r8 + sched_barrier(0) pinning the ds_read/STAGE cluster BEFORE each
// mid-phase s_barrier (hipcc sinks LDS loads past s_barrier otherwise -> fully
// serialized phases; r8 measured 6670 cyc/tile == serial model).

typedef _Float16 f16;
typedef __attribute__((ext_vector_type(8))) _Float16 f16x8;
typedef __attribute__((ext_vector_type(4))) _Float16 f16x4;
typedef __attribute__((ext_vector_type(4))) float f32x4;

#define BATCH 8192
#define IN_DIM 1024
#define HID 2048

__device__ __forceinline__ float fast_tanh(float x) {
  x = fminf(12.0f, fmaxf(-12.0f, x));
  float e = __expf(2.0f * x);
  return (e - 1.0f) * __builtin_amdgcn_rcpf(e + 1.0f);
}

// ---- cast f32 -> f16 ------------------------------------------------------
__global__ __launch_bounds__(256) void cast_kernel(const float* __restrict__ in,
                                                   f16* __restrict__ out, int n4) {
  int i = blockIdx.x * blockDim.x + threadIdx.x;
  if (i < n4) {
    float4 v = reinterpret_cast<const float4*>(in)[i];
    f16x4 o = { (f16)v.x, (f16)v.y, (f16)v.z, (f16)v.w };
    reinterpret_cast<f16x4*>(out)[i] = o;
  }
}

// ---- fused transpose+cast for all 3 weights ------------------------------
__global__ __launch_bounds__(256) void transpose_cast3(
    const float* __restrict__ W1, const float* __restrict__ W2,
    const float* __restrict__ W3, f16* __restrict__ w1t,
    f16* __restrict__ w2t, f16* __restrict__ w3t) {
  __shared__ float tile[32][33];
  int b = blockIdx.x;
  const float* W; f16* Wt; int K, N;
  if (b < 2048)      { W = W1; Wt = w1t; K = IN_DIM; N = HID; }
  else if (b < 6144) { W = W2; Wt = w2t; K = HID;    N = HID; b -= 2048; }
  else               { W = W3; Wt = w3t; K = HID;    N = HID; b -= 6144; }
  const int nbt = N / 32;
  const int nb = (b % nbt) * 32, kb = (b / nbt) * 32;
  const int tx = threadIdx.x, ty = threadIdx.y;  // 32 x 8
#pragma unroll
  for (int i = 0; i < 4; ++i)
    tile[ty + i * 8][tx] = W[(size_t)(kb + ty + i * 8) * N + nb + tx];
  __syncthreads();
#pragma unroll
  for (int i = 0; i < 4; ++i)
    Wt[(size_t)(nb + ty + i * 8) * K + kb + tx] = (f16)tile[tx][ty + i * 8];
}

// ---- 256x256 GEMM + bias + tanh, 8-phase schedule ------------------------
// Structure identical to r8 (layout, staging, gates, hazards all verified);
// ONLY change: __builtin_amdgcn_sched_barrier(0) before each mid-phase
// s_barrier so the emitted ds_reads+GLDS stay ABOVE the barrier. They then
// drain during barrier-arrival/other waves' MFMA, and per-wave lgkmcnt(0)
// completion order staggers MFMA starts -> LDS pipe and MFMA pipe overlap.

#define GLDS16(g, l)                                                         \
  __builtin_amdgcn_global_load_lds(                                          \
      (const __attribute__((address_space(1))) unsigned int*)(g),            \
      (__attribute__((address_space(3))) unsigned int*)(l), 16, 0, 0)

template <int K>
__global__ __launch_bounds__(512, 2) void gemm256_bias_tanh(
    const f16* __restrict__ A,      // [8192 x K]
    const f16* __restrict__ Bt,     // [2048 x K]
    const float* __restrict__ bias, // [2048]
    f16* __restrict__ Out) {        // [8192 x 2048]
  constexpr int NT = K / 64;
  __shared__ f16 smem[65536];       // A: [b*16384 + u*8192), B: +32768

  const int T = threadIdx.x;
  const int l = T & 63;
  const int w = T >> 6;
  const int wm = w >> 2, wn = w & 3;   // wave grid 2(M) x 4(N)
  const int lr = l & 15, lc = l >> 4;

  const int bm = (int)blockIdx.x >> 3; // 32 m-tiles
  const int bn = (int)blockIdx.x & 7;  // 8 n-tiles
  const int tm = bm << 8, tn = bn << 8;

  // frag read bases (elems within a k-half subtile)
  const int abase = (wm * 16 + (lr >> 3)) * 256 + lc * 64 + (lr & 7) * 8;
  const int bbase = (wn * 8 + (lr >> 3)) * 256 + lc * 64 + (lr & 7) * 8;

  // staging maps: chunk-in-half cc -> row=((cc>>5)<<3)|(cc&7), k=((cc>>3)&3)*8
  const int ccA0 = wm * 512 + wn * 128 + l;
  const int ccA1 = ccA0 + 64;
  const int ccB0 = (wn >> 1) * 512 + (wm * 2 + (wn & 1)) * 128 + l;
  const int ccB1 = ccB0 + 64;
#define ROWOF(cc) ((((cc) >> 5) << 3) | ((cc) & 7))
#define KLOF(cc) ((((cc) >> 3) & 3) * 8)
  const f16* pa0 = A + (size_t)(tm + ROWOF(ccA0)) * K + KLOF(ccA0);
  const f16* pa1 = A + (size_t)(tm + ROWOF(ccA1)) * K + KLOF(ccA1);
  const f16* pb0 = Bt + (size_t)(tn + ROWOF(ccB0)) * K + KLOF(ccB0);
  const f16* pb1 = Bt + (size_t)(tn + ROWOF(ccB1)) * K + KLOF(ccB1);
  const int dA = wm * 4096 + wn * 1024;
  const int dB = 32768 + (wn >> 1) * 4096 + (wm * 2 + (wn & 1)) * 1024;

#define STAGE_A(tt, u)                                                       \
  do {                                                                       \
    const int _b = ((tt) & 1) * 16384 + (u) * 8192;                          \
    GLDS16(pa0 + (tt) * 64 + (u) * 32, &smem[_b + dA]);                      \
    GLDS16(pa1 + (tt) * 64 + (u) * 32, &smem[_b + dA + 512]);                \
  } while (0)
#define STAGE_B(tt, u)                                                       \
  do {                                                                       \
    const int _b = ((tt) & 1) * 16384 + (u) * 8192;                          \
    GLDS16(pb0 + (tt) * 64 + (u) * 32, &smem[_b + dB]);                      \
    GLDS16(pb1 + (tt) * 64 + (u) * 32, &smem[_b + dB + 512]);                \
  } while (0)
#define LDF(p) (*reinterpret_cast<const f16x8*>(p))
#define MFMA4(base)                                                          \
  _Pragma("unroll") for (int mi = 0; mi < 4; ++mi)                           \
  _Pragma("unroll") for (int ni = 0; ni < 4; ++ni)                           \
      acc[(base) + mi][ni] = __builtin_amdgcn_mfma_f32_16x16x32_f16(         \
          afr[mi], bfr[ni], acc[(base) + mi][ni], 0, 0, 0);
// pin reads/stages ABOVE the barrier; wait own lgkm AFTER it; fence MFMA below
#define PHASE_SYNC()                                                         \
  __builtin_amdgcn_sched_barrier(0);                                         \
  __builtin_amdgcn_s_barrier();                                              \
  asm volatile("s_waitcnt lgkmcnt(0)" ::: "memory");                         \
  __builtin_amdgcn_sched_barrier(0);

  f32x4 acc[8][4] = {};

  // ---- prologue: stage tile 0's 4 units ----
  STAGE_A(0, 0); STAGE_B(0, 0); STAGE_A(0, 1); STAGE_B(0, 1);
  asm volatile("s_waitcnt vmcnt(4)" ::: "memory");  // Au0,Bu0 landed
  __builtin_amdgcn_s_barrier();

  for (int t = 0; t < NT; ++t) {
    const int bo = (t & 1) * 16384;
    const f16* As0 = smem + bo;                 // k-half 0
    const f16* As1 = smem + bo + 8192;          // k-half 1
    const f16* Bs0 = smem + 32768 + bo;
    const f16* Bs1 = smem + 32768 + bo + 8192;
    f16x8 afr[4], bfr[4];

    // ===== P1: reads B(ks0) + A(mh0,ks0); stage (t+1).Au0 =====
#pragma unroll
    for (int ni = 0; ni < 4; ++ni) bfr[ni] = LDF(Bs0 + bbase + ni * 512);
#pragma unroll
    for (int mi = 0; mi < 4; ++mi) afr[mi] = LDF(As0 + abase + mi * 512);
    if (t + 1 < NT) STAGE_A(t + 1, 0);
    PHASE_SYNC()
    __builtin_amdgcn_s_setprio(1);
    MFMA4(0)
    __builtin_amdgcn_s_setprio(0);
    __builtin_amdgcn_s_barrier();

    // ===== P2: reads A(mh1,ks0); stage (t+1).Bu0; gate vmcnt =====
#pragma unroll
    for (int mi = 0; mi < 4; ++mi) afr[mi] = LDF(As0 + abase + (4 + mi) * 512);
    if (t + 1 < NT) STAGE_B(t + 1, 0);
    PHASE_SYNC()
    __builtin_amdgcn_s_setprio(1);
    MFMA4(4)
    __builtin_amdgcn_s_setprio(0);
    if (t + 1 < NT) {
      asm volatile("s_waitcnt vmcnt(4)" ::: "memory");  // Au1(t),Bu1(t) landed
    } else {
      asm volatile("s_waitcnt vmcnt(0)" ::: "memory");  // tail drain
    }
    __builtin_amdgcn_s_barrier();

    // ===== P3: reads B(ks1) + A(mh0,ks1); stage (t+1).Au1 =====
#pragma unroll
    for (int ni = 0; ni < 4; ++ni) bfr[ni] = LDF(Bs1 + bbase + ni * 512);
#pragma unroll
    for (int mi = 0; mi < 4; ++mi) afr[mi] = LDF(As1 + abase + mi * 512);
    if (t + 1 < NT) STAGE_A(t + 1, 1);
    PHASE_SYNC()
    __builtin_amdgcn_s_setprio(1);
    MFMA4(0)
    __builtin_amdgcn_s_setprio(0);
    __builtin_amdgcn_s_barrier();

    // ===== P4: reads A(mh1,ks1); stage (t+1).Bu1; gate vmcnt =====
#pragma unroll
    for (int mi = 0; mi < 4; ++mi) afr[mi] = LDF(As1 + abase + (4 + mi) * 512);
    if (t + 1 < NT) STAGE_B(t + 1, 1);
    PHASE_SYNC()
    __builtin_amdgcn_s_setprio(1);
    MFMA4(4)
    __builtin_amdgcn_s_setprio(0);
    if (t + 1 < NT) {
      asm volatile("s_waitcnt vmcnt(4)" ::: "memory");  // Au0,Bu0(t+1) landed
    }
    __builtin_amdgcn_s_barrier();
  }

  __syncthreads();  // full fence before reusing LDS as epilogue bounce

  // ---- epilogue: bias+tanh -> LDS bounce (XOR swizzle) -> coalesced store
  // D frag: col=lane&15, row=(lane>>4)*4+j. byte(r,c)=r*512+((c*2)^((r&7)<<4))
#pragma unroll
  for (int ni = 0; ni < 4; ++ni) {
    const int col = wn * 64 + ni * 16 + lr;
    const float bv = bias[tn + col];
#pragma unroll
    for (int mi = 0; mi < 8; ++mi) {
      const int r0 = wm * 128 + mi * 16 + ((l >> 4) << 2);
#pragma unroll
      for (int j = 0; j < 4; ++j) {
        const int r = r0 + j;
        const int bo2 = r * 512 + ((col * 2) ^ ((r & 7) << 4));
        *reinterpret_cast<f16*>(reinterpret_cast<char*>(smem) + bo2) =
            (f16)fast_tanh(acc[mi][ni][j] + bv);
      }
    }
  }
  __syncthreads();
#pragma unroll
  for (int it = 0; it < 16; ++it) {
    const int r = w * 32 + it * 2 + (l >> 5);
    const int cb = (l & 31) * 16;
    const int so = r * 512 + (cb ^ ((r & 7) << 4));
    f16x8 v = *reinterpret_cast<const f16x8*>(
        reinterpret_cast<const char*>(smem) + so);
    *reinterpret_cast<f16x8*>(
        reinterpret_cast<char*>(Out + (size_t)(tm + r) * HID + tn) + cb) = v;
  }
#undef STAGE_A
#undef STAGE_B
#undef LDF
#undef MFMA4
#undef PHASE_SYNC
#undef ROWOF
#undef KLOF
}

// ---- final: out[b] = sum_n s(core[b,n]) * Wout[n] + bout -----------------
__global__ __launch_bounds__(256) void final_reduce(
    const f16* __restrict__ core, const float* __restrict__ Wout,
    const float* __restrict__ bout, const float* __restrict__ weight,
    const float* __restrict__ qbias, const float* __restrict__ qscale,
    const float* __restrict__ qshift, float* __restrict__ out) {
  const int b = blockIdx.x, t = threadIdx.x;
  const float sw = __sinf(weight[0]);
  const float qb = qbias[0], qs = qscale[0], qsh = qshift[0];
  f16x8 c8 = *reinterpret_cast<const f16x8*>(&core[(size_t)b * HID + t * 8]);
  float sum = 0.f;
#pragma unroll
  for (int j = 0; j < 8; ++j) {
    float c = (float)c8[j];
    float s = c + (sw * __sinf(c) + qb) * qs + qsh;
    sum += s * Wout[t * 8 + j];
  }
#pragma unroll
  for (int off = 32; off >= 1; off >>= 1) sum += __shfl_down(sum, off, 64);
  __shared__ float red[4];
  if ((t & 63) == 0) red[t >> 6] = sum;
  __syncthreads();
  if (t == 0) out[b] = red[0] + red[1] + red[2] + red[3] + bout[0];
}

extern "C" void kernel_launch(void* const* d_in, const int* in_sizes, int n_in,
                              void* d_out, int out_size, void* d_ws, size_t ws_size,
                              hipStream_t stream) {
  const float* x    = (const float*)d_in[0];
  const float* W1   = (const float*)d_in[1];
  const float* b1   = (const float*)d_in[2];
  const float* W2   = (const float*)d_in[3];
  const float* b2   = (const float*)d_in[4];
  const float* W3   = (const float*)d_in[5];
  const float* b3   = (const float*)d_in[6];
  const float* Wout = (const float*)d_in[7];
  const float* bout = (const float*)d_in[8];
  const float* wgt  = (const float*)d_in[9];
  const float* qb   = (const float*)d_in[10];
  const float* qs   = (const float*)d_in[11];
  const float* qsh  = (const float*)d_in[12];
  float* out = (float*)d_out;

  char* ws = (char*)d_ws;
  size_t off = 0;
  f16* xh  = (f16*)(ws + off); off += (size_t)BATCH * IN_DIM * sizeof(f16);
  f16* w1t = (f16*)(ws + off); off += (size_t)HID * IN_DIM * sizeof(f16);
  f16* w2t = (f16*)(ws + off); off += (size_t)HID * HID * sizeof(f16);
  f16* w3t = (f16*)(ws + off); off += (size_t)HID * HID * sizeof(f16);
  f16* h1  = (f16*)(ws + off); off += (size_t)BATCH * HID * sizeof(f16);
  f16* h2  = (f16*)(ws + off); off += (size_t)BATCH * HID * sizeof(f16);

  {
    int n4 = BATCH * IN_DIM / 4;
    cast_kernel<<<(n4 + 255) / 256, 256, 0, stream>>>(x, xh, n4);
  }
  {
    dim3 blk(32, 8);
    transpose_cast3<<<10240, blk, 0, stream>>>(W1, W2, W3, w1t, w2t, w3t);
  }
  const int grid = (BATCH / 256) * (HID / 256);  // 256 blocks = 1/CU
  gemm256_bias_tanh<IN_DIM><<<grid, 512, 0, stream>>>(xh, w1t, b1, h1);
  gemm256_bias_tanh<HID>   <<<grid, 512, 0, stream>>>(h1, w2t, b2, h2);
  gemm256_bias_tanh<HID>   <<<grid, 512, 0, stream>>>(h2, w3t, b3, h1);
  final_reduce<<<BATCH, 256, 0, stream>>>(h1, Wout, bout, wgt, qb, qs, qsh, out);
}